// Round 2
// baseline (1419.333 us; speedup 1.0000x reference)
//
#include <hip/hip_runtime.h>
#include <hip/hip_bf16.h>

#define D 64

// ---------------- int64-vs-int32 edge_index detection ----------------
__global__ void detect_kernel(const unsigned int* e32, int* flag) {
    __shared__ int nz;
    if (threadIdx.x == 0) nz = 0;
    __syncthreads();
    if (e32[2 * threadIdx.x + 1] != 0) nz = 1;
    __syncthreads();
    if (threadIdx.x == 0) *flag = (nz == 0) ? 1 : 0;
}

__device__ __forceinline__ int load_idx(const void* e, int is64, long long i) {
    if (is64) return (int)((const long long*)e)[i];
    return ((const int*)e)[i];
}

// ---------------- degree histogram ----------------
__global__ void deg_count_kernel(const void* edges, const int* flag, int* degi, int E) {
    int e = blockIdx.x * 256 + threadIdx.x;
    if (e >= E) return;
    int is64 = *flag;
    int dst = load_idx(edges, is64, (long long)E + e);
    atomicAdd(&degi[dst], 1);
}

__global__ void dinv_kernel(const int* degi, float* dinv, int n) {
    int v = blockIdx.x * 256 + threadIdx.x;
    if (v >= n) return;
    dinv[v] = rsqrtf((float)(degi[v] + 1));
}

// ---------------- exclusive scan ----------------
__global__ __launch_bounds__(1024) void scanA_kernel(const int* deg, int* offs, int* bsums, int n) {
    __shared__ int s[1024];
    int tid = threadIdx.x;
    int i = blockIdx.x * 1024 + tid;
    int v = (i < n) ? deg[i] : 0;
    s[tid] = v;
    __syncthreads();
    for (int d = 1; d < 1024; d <<= 1) {
        int t = (tid >= d) ? s[tid - d] : 0;
        __syncthreads();
        s[tid] += t;
        __syncthreads();
    }
    if (i < n) offs[i] = s[tid] - v;
    if (tid == 1023) bsums[blockIdx.x] = s[1023];
}

__global__ __launch_bounds__(1024) void scanB_kernel(int* bsums, int nb) {
    __shared__ int s[1024];
    int tid = threadIdx.x;
    int v = (tid < nb) ? bsums[tid] : 0;
    s[tid] = v;
    __syncthreads();
    for (int d = 1; d < 1024; d <<= 1) {
        int t = (tid >= d) ? s[tid - d] : 0;
        __syncthreads();
        s[tid] += t;
        __syncthreads();
    }
    if (tid < nb) bsums[tid] = s[tid] - v;
}

__global__ __launch_bounds__(1024) void scanC_kernel(int* offs, const int* bsums, int* fillptr,
                                                     int n, int E) {
    int i = blockIdx.x * 1024 + threadIdx.x;
    if (i < n) {
        int o = offs[i] + bsums[blockIdx.x];
        offs[i] = o;
        fillptr[i] = o;
    }
    if (i == 0) offs[n] = E;
}

// ---------------- CSR fill: packed (src, norm) meta ----------------
__global__ void fill_kernel(const void* edges, const int* flag, const float* dinv,
                            int* fillptr, int2* meta, int E) {
    int e = blockIdx.x * 256 + threadIdx.x;
    if (e >= E) return;
    int is64 = *flag;
    int s = load_idx(edges, is64, e);
    int d = load_idx(edges, is64, (long long)E + e);
    int pos = atomicAdd(&fillptr[d], 1);
    meta[pos] = make_int2(s, __float_as_int(dinv[s] * dinv[d]));
}

// ---------------- fused (BN+ReLU) -> [n,64]@[64,64] matmul ----------------
// W column per lane in 64 VGPRs; X tile (16 rows) staged in LDS with BN+ReLU
// applied during staging; broadcast ds_read_b128 for X, 4 rows per wave.
__global__ __launch_bounds__(256, 4) void mm_bn_kernel(
    const float* __restrict__ X, const float* __restrict__ W,
    const float* __restrict__ stats, const float* __restrict__ gamma,
    const float* __restrict__ beta, int use_bn, float inv_n,
    float* __restrict__ Y, int n) {
    int lane = threadIdx.x & 63;
    int wid = threadIdx.x >> 6;

    float wcol[64];
#pragma unroll
    for (int k = 0; k < 64; k++) wcol[k] = W[k * 64 + lane];

    __shared__ float scale_s[64], shift_s[64];
    __shared__ float Xs[16 * 64];
    if (threadIdx.x < 64) {
        float sc = 1.f, sh = 0.f;
        if (use_bn) {
            int f = threadIdx.x;
            float m = stats[f] * inv_n;
            float var = stats[64 + f] * inv_n - m * m;
            float rs = rsqrtf(var + 1e-5f);
            sc = rs * gamma[f];
            sh = beta[f] - m * sc;
        }
        scale_s[threadIdx.x] = sc;
        shift_s[threadIdx.x] = sh;
    }

    long long total = (long long)n * 64;
    int ntiles = (n + 15) >> 4;
    for (int t = blockIdx.x; t < ntiles; t += gridDim.x) {
        __syncthreads();  // protect Xs (prev iter) + params (first iter)
        long long base = (long long)t * 1024;
        int i4 = threadIdx.x * 4;
        float4 v = make_float4(0.f, 0.f, 0.f, 0.f);
        if (base + i4 + 3 < total) {
            v = *(const float4*)(X + base + i4);
        } else {
            if (base + i4 + 0 < total) v.x = X[base + i4 + 0];
            if (base + i4 + 1 < total) v.y = X[base + i4 + 1];
            if (base + i4 + 2 < total) v.z = X[base + i4 + 2];
        }
        int f0 = i4 & 63;  // 4-aligned, never wraps within float4
        v.x = v.x * scale_s[f0 + 0] + shift_s[f0 + 0];
        v.y = v.y * scale_s[f0 + 1] + shift_s[f0 + 1];
        v.z = v.z * scale_s[f0 + 2] + shift_s[f0 + 2];
        v.w = v.w * scale_s[f0 + 3] + shift_s[f0 + 3];
        if (use_bn) {
            v.x = fmaxf(v.x, 0.f);
            v.y = fmaxf(v.y, 0.f);
            v.z = fmaxf(v.z, 0.f);
            v.w = fmaxf(v.w, 0.f);
        }
        *(float4*)(Xs + i4) = v;
        __syncthreads();

        const float* x0 = Xs + (wid * 4 + 0) * 64;
        const float* x1 = Xs + (wid * 4 + 1) * 64;
        const float* x2 = Xs + (wid * 4 + 2) * 64;
        const float* x3 = Xs + (wid * 4 + 3) * 64;
        float acc0 = 0.f, acc1 = 0.f, acc2 = 0.f, acc3 = 0.f;
#pragma unroll
        for (int k = 0; k < 64; k += 4) {
            float4 a = *(const float4*)(x0 + k);
            float4 b = *(const float4*)(x1 + k);
            float4 c = *(const float4*)(x2 + k);
            float4 d = *(const float4*)(x3 + k);
            acc0 += a.x * wcol[k] + a.y * wcol[k + 1] + a.z * wcol[k + 2] + a.w * wcol[k + 3];
            acc1 += b.x * wcol[k] + b.y * wcol[k + 1] + b.z * wcol[k + 2] + b.w * wcol[k + 3];
            acc2 += c.x * wcol[k] + c.y * wcol[k + 1] + c.z * wcol[k + 2] + c.w * wcol[k + 3];
            acc3 += d.x * wcol[k] + d.y * wcol[k + 1] + d.z * wcol[k + 2] + d.w * wcol[k + 3];
        }
        int r0 = t * 16 + wid * 4;
        if (r0 + 0 < n) Y[(long long)(r0 + 0) * 64 + lane] = acc0;
        if (r0 + 1 < n) Y[(long long)(r0 + 1) * 64 + lane] = acc1;
        if (r0 + 2 < n) Y[(long long)(r0 + 2) * 64 + lane] = acc2;
        if (r0 + 3 < n) Y[(long long)(r0 + 3) * 64 + lane] = acc3;
    }
}

// ---------------- aggregation: one wave per dst, lane = feature, 8-way MLP ----
__global__ __launch_bounds__(256) void agg_kernel(const float* __restrict__ T,
                                                  const int* __restrict__ offs,
                                                  const int2* __restrict__ meta,
                                                  const float* __restrict__ dinv,
                                                  const float* __restrict__ bias,
                                                  float* __restrict__ out, int n) {
    int v = blockIdx.x * 4 + (threadIdx.x >> 6);
    if (v >= n) return;
    int lane = threadIdx.x & 63;
    float di = dinv[v];
    float acc = di * di * T[(long long)v * D + lane];  // self-loop
    int j = offs[v], j1 = offs[v + 1];
    for (; j + 8 <= j1; j += 8) {
        int2 m0 = meta[j + 0], m1 = meta[j + 1], m2 = meta[j + 2], m3 = meta[j + 3];
        int2 m4 = meta[j + 4], m5 = meta[j + 5], m6 = meta[j + 6], m7 = meta[j + 7];
        float t0 = T[(long long)m0.x * D + lane];
        float t1 = T[(long long)m1.x * D + lane];
        float t2 = T[(long long)m2.x * D + lane];
        float t3 = T[(long long)m3.x * D + lane];
        float t4 = T[(long long)m4.x * D + lane];
        float t5 = T[(long long)m5.x * D + lane];
        float t6 = T[(long long)m6.x * D + lane];
        float t7 = T[(long long)m7.x * D + lane];
        acc += __int_as_float(m0.y) * t0;
        acc += __int_as_float(m1.y) * t1;
        acc += __int_as_float(m2.y) * t2;
        acc += __int_as_float(m3.y) * t3;
        acc += __int_as_float(m4.y) * t4;
        acc += __int_as_float(m5.y) * t5;
        acc += __int_as_float(m6.y) * t6;
        acc += __int_as_float(m7.y) * t7;
    }
    for (; j + 4 <= j1; j += 4) {
        int2 m0 = meta[j + 0], m1 = meta[j + 1], m2 = meta[j + 2], m3 = meta[j + 3];
        float t0 = T[(long long)m0.x * D + lane];
        float t1 = T[(long long)m1.x * D + lane];
        float t2 = T[(long long)m2.x * D + lane];
        float t3 = T[(long long)m3.x * D + lane];
        acc += __int_as_float(m0.y) * t0;
        acc += __int_as_float(m1.y) * t1;
        acc += __int_as_float(m2.y) * t2;
        acc += __int_as_float(m3.y) * t3;
    }
    for (; j < j1; j++) {
        int2 m = meta[j];
        acc += __int_as_float(m.y) * T[(long long)m.x * D + lane];
    }
    out[(long long)v * D + lane] = acc + bias[lane];
}

// ---------------- batchnorm stats ----------------
__global__ __launch_bounds__(256) void bnstats_kernel(const float* __restrict__ H,
                                                      float* __restrict__ stats, int n) {
    int f = threadIdx.x & 63;
    int r = threadIdx.x >> 6;
    float s = 0.f, q = 0.f;
    for (int node = blockIdx.x * 4 + r; node < n; node += gridDim.x * 4) {
        float x = H[(long long)node * D + f];
        s += x;
        q += x * x;
    }
    __shared__ float ls[256], lq[256];
    ls[threadIdx.x] = s;
    lq[threadIdx.x] = q;
    __syncthreads();
    if (r == 0) {
        s = ls[f] + ls[64 + f] + ls[128 + f] + ls[192 + f];
        q = lq[f] + lq[64 + f] + lq[128 + f] + lq[192 + f];
        atomicAdd(&stats[f], s);
        atomicAdd(&stats[64 + f], q);
    }
}

// ---------------- host ----------------
extern "C" void kernel_launch(void* const* d_in, const int* in_sizes, int n_in,
                              void* d_out, int out_size, void* d_ws, size_t ws_size,
                              hipStream_t stream) {
    const float* x = (const float*)d_in[0];
    const void* edges = d_in[1];
    const float* W1 = (const float*)d_in[3];
    const float* b1 = (const float*)d_in[4];
    const float* gamma1 = (const float*)d_in[5];
    const float* beta1 = (const float*)d_in[6];
    const float* W2 = (const float*)d_in[7];
    const float* b2 = (const float*)d_in[8];
    const float* gamma2 = (const float*)d_in[9];
    const float* beta2 = (const float*)d_in[10];
    const float* W3 = (const float*)d_in[11];
    const float* b3 = (const float*)d_in[12];

    const int N = in_sizes[0] / D;
    const int E = in_sizes[1] / 2;
    const float inv_n = 1.f / (float)N;

    char* ws = (char*)d_ws;
    size_t off = 0;
    auto alloc = [&](size_t bytes) -> void* {
        void* p = ws + off;
        off = (off + bytes + 255) & ~(size_t)255;
        return p;
    };
    float* dinv  = (float*)alloc((size_t)N * 4);
    int*   degi  = (int*)  alloc((size_t)N * 4);
    int*   offs  = (int*)  alloc((size_t)(N + 1) * 4);
    int*   fillp = (int*)  alloc((size_t)N * 4);
    int2*  meta  = (int2*) alloc((size_t)E * 8);
    int*   bsums = (int*)  alloc(1024 * 4);
    int*   flag  = (int*)  alloc(4);
    float* stats = (float*)alloc(128 * 4);
    float* bufA  = (float*)alloc((size_t)N * D * 4);
    float* hbuf  = (float*)d_out;  // ping-pong; fully overwritten each layer

    const int eb = (E + 255) / 256;
    const int nb256 = (N + 255) / 256;
    const int nb1024 = (N + 1023) / 1024;
    const int aggb = (N + 3) / 4;

    // ---- build CSR (once, reused 3x) ----
    hipMemsetAsync(degi, 0, (size_t)N * 4, stream);
    detect_kernel<<<1, 256, 0, stream>>>((const unsigned int*)edges, flag);
    deg_count_kernel<<<eb, 256, 0, stream>>>(edges, flag, degi, E);
    dinv_kernel<<<nb256, 256, 0, stream>>>(degi, dinv, N);
    scanA_kernel<<<nb1024, 1024, 0, stream>>>(degi, offs, bsums, N);
    scanB_kernel<<<1, 1024, 0, stream>>>(bsums, nb1024);
    scanC_kernel<<<nb1024, 1024, 0, stream>>>(offs, bsums, fillp, N, E);
    fill_kernel<<<eb, 256, 0, stream>>>(edges, flag, dinv, fillp, meta, E);

    // ---- layer 1 ----
    mm_bn_kernel<<<1024, 256, 0, stream>>>(x, W1, nullptr, nullptr, nullptr, 0, inv_n, bufA, N);
    agg_kernel<<<aggb, 256, 0, stream>>>(bufA, offs, meta, dinv, b1, hbuf, N);
    hipMemsetAsync(stats, 0, 128 * 4, stream);
    bnstats_kernel<<<512, 256, 0, stream>>>(hbuf, stats, N);

    // ---- layer 2 (BN1+ReLU fused into matmul staging) ----
    mm_bn_kernel<<<1024, 256, 0, stream>>>(hbuf, W2, stats, gamma1, beta1, 1, inv_n, bufA, N);
    agg_kernel<<<aggb, 256, 0, stream>>>(bufA, offs, meta, dinv, b2, hbuf, N);
    hipMemsetAsync(stats, 0, 128 * 4, stream);
    bnstats_kernel<<<512, 256, 0, stream>>>(hbuf, stats, N);

    // ---- layer 3 (BN2+ReLU fused; no BN after) ----
    mm_bn_kernel<<<1024, 256, 0, stream>>>(hbuf, W3, stats, gamma2, beta2, 1, inv_n, bufA, N);
    agg_kernel<<<aggb, 256, 0, stream>>>(bufA, offs, meta, dinv, b3, (float*)d_out, N);
}

// Round 3
// 672.005 us; speedup vs baseline: 2.1121x; 2.1121x over previous
//
#include <hip/hip_runtime.h>
#include <hip/hip_bf16.h>

#define D 64

// ---------------- int64-vs-int32 edge_index detection ----------------
__global__ void detect_kernel(const unsigned int* e32, int* flag) {
    __shared__ int nz;
    if (threadIdx.x == 0) nz = 0;
    __syncthreads();
    if (e32[2 * threadIdx.x + 1] != 0) nz = 1;
    __syncthreads();
    if (threadIdx.x == 0) *flag = (nz == 0) ? 1 : 0;
}

__device__ __forceinline__ int load_idx(const void* e, int is64, long long i) {
    if (is64) return (int)((const long long*)e)[i];
    return ((const int*)e)[i];
}

// ---------------- degree histogram ----------------
__global__ void deg_count_kernel(const void* edges, const int* flag, int* degi, int E) {
    int e = blockIdx.x * 256 + threadIdx.x;
    if (e >= E) return;
    int is64 = *flag;
    int dst = load_idx(edges, is64, (long long)E + e);
    atomicAdd(&degi[dst], 1);
}

__global__ void dinv_kernel(const int* degi, float* dinv, int n) {
    int v = blockIdx.x * 256 + threadIdx.x;
    if (v >= n) return;
    dinv[v] = rsqrtf((float)(degi[v] + 1));
}

// ---------------- exclusive scan ----------------
__global__ __launch_bounds__(1024) void scanA_kernel(const int* deg, int* offs, int* bsums, int n) {
    __shared__ int s[1024];
    int tid = threadIdx.x;
    int i = blockIdx.x * 1024 + tid;
    int v = (i < n) ? deg[i] : 0;
    s[tid] = v;
    __syncthreads();
    for (int d = 1; d < 1024; d <<= 1) {
        int t = (tid >= d) ? s[tid - d] : 0;
        __syncthreads();
        s[tid] += t;
        __syncthreads();
    }
    if (i < n) offs[i] = s[tid] - v;
    if (tid == 1023) bsums[blockIdx.x] = s[1023];
}

__global__ __launch_bounds__(1024) void scanB_kernel(int* bsums, int nb) {
    __shared__ int s[1024];
    int tid = threadIdx.x;
    int v = (tid < nb) ? bsums[tid] : 0;
    s[tid] = v;
    __syncthreads();
    for (int d = 1; d < 1024; d <<= 1) {
        int t = (tid >= d) ? s[tid - d] : 0;
        __syncthreads();
        s[tid] += t;
        __syncthreads();
    }
    if (tid < nb) bsums[tid] = s[tid] - v;
}

__global__ __launch_bounds__(1024) void scanC_kernel(int* offs, const int* bsums, int* fillptr,
                                                     int n, int E) {
    int i = blockIdx.x * 1024 + threadIdx.x;
    if (i < n) {
        int o = offs[i] + bsums[blockIdx.x];
        offs[i] = o;
        fillptr[i] = o;
    }
    if (i == 0) offs[n] = E;
}

// ---------------- CSR fill: packed (src, norm) meta ----------------
__global__ void fill_kernel(const void* edges, const int* flag, const float* dinv,
                            int* fillptr, int2* meta, int E) {
    int e = blockIdx.x * 256 + threadIdx.x;
    if (e >= E) return;
    int is64 = *flag;
    int s = load_idx(edges, is64, e);
    int d = load_idx(edges, is64, (long long)E + e);
    int pos = atomicAdd(&fillptr[d], 1);
    meta[pos] = make_int2(s, __float_as_int(dinv[s] * dinv[d]));
}

// ---------------- fused (BN+ReLU) -> [n,64]@[64,64] matmul ----------------
// W column per lane in 64 VGPRs (NEEDS >=100 VGPRs: launch_bounds(256,2) ->
// 128-VGPR budget; (256,4) capped at 64 and spilled wcol to scratch, 1.5 GB
// HBM traffic per dispatch — round-2 regression).
__global__ __launch_bounds__(256, 2) void mm_bn_kernel(
    const float* __restrict__ X, const float* __restrict__ W,
    const float* __restrict__ stats, const float* __restrict__ gamma,
    const float* __restrict__ beta, int use_bn, float inv_n,
    float* __restrict__ Y, int n) {
    int lane = threadIdx.x & 63;
    int wid = threadIdx.x >> 6;

    float wcol[64];
#pragma unroll
    for (int k = 0; k < 64; k++) wcol[k] = W[k * 64 + lane];

    __shared__ float scale_s[64], shift_s[64];
    __shared__ float Xs[16 * 64];
    if (threadIdx.x < 64) {
        float sc = 1.f, sh = 0.f;
        if (use_bn) {
            int f = threadIdx.x;
            float m = stats[f] * inv_n;
            float var = stats[64 + f] * inv_n - m * m;
            float rs = rsqrtf(var + 1e-5f);
            sc = rs * gamma[f];
            sh = beta[f] - m * sc;
        }
        scale_s[threadIdx.x] = sc;
        shift_s[threadIdx.x] = sh;
    }

    long long total = (long long)n * 64;
    int ntiles = (n + 15) >> 4;
    for (int t = blockIdx.x; t < ntiles; t += gridDim.x) {
        __syncthreads();  // protect Xs (prev iter) + params (first iter)
        long long base = (long long)t * 1024;
        int i4 = threadIdx.x * 4;
        float4 v = make_float4(0.f, 0.f, 0.f, 0.f);
        if (base + i4 + 3 < total) {
            v = *(const float4*)(X + base + i4);
        } else {
            if (base + i4 + 0 < total) v.x = X[base + i4 + 0];
            if (base + i4 + 1 < total) v.y = X[base + i4 + 1];
            if (base + i4 + 2 < total) v.z = X[base + i4 + 2];
        }
        int f0 = i4 & 63;  // 4-aligned, never wraps within float4
        v.x = v.x * scale_s[f0 + 0] + shift_s[f0 + 0];
        v.y = v.y * scale_s[f0 + 1] + shift_s[f0 + 1];
        v.z = v.z * scale_s[f0 + 2] + shift_s[f0 + 2];
        v.w = v.w * scale_s[f0 + 3] + shift_s[f0 + 3];
        if (use_bn) {
            v.x = fmaxf(v.x, 0.f);
            v.y = fmaxf(v.y, 0.f);
            v.z = fmaxf(v.z, 0.f);
            v.w = fmaxf(v.w, 0.f);
        }
        *(float4*)(Xs + i4) = v;
        __syncthreads();

        const float* x0 = Xs + (wid * 4 + 0) * 64;
        const float* x1 = Xs + (wid * 4 + 1) * 64;
        const float* x2 = Xs + (wid * 4 + 2) * 64;
        const float* x3 = Xs + (wid * 4 + 3) * 64;
        float acc0 = 0.f, acc1 = 0.f, acc2 = 0.f, acc3 = 0.f;
#pragma unroll
        for (int k = 0; k < 64; k += 4) {
            float4 a = *(const float4*)(x0 + k);
            float4 b = *(const float4*)(x1 + k);
            float4 c = *(const float4*)(x2 + k);
            float4 d = *(const float4*)(x3 + k);
            acc0 += a.x * wcol[k] + a.y * wcol[k + 1] + a.z * wcol[k + 2] + a.w * wcol[k + 3];
            acc1 += b.x * wcol[k] + b.y * wcol[k + 1] + b.z * wcol[k + 2] + b.w * wcol[k + 3];
            acc2 += c.x * wcol[k] + c.y * wcol[k + 1] + c.z * wcol[k + 2] + c.w * wcol[k + 3];
            acc3 += d.x * wcol[k] + d.y * wcol[k + 1] + d.z * wcol[k + 2] + d.w * wcol[k + 3];
        }
        int r0 = t * 16 + wid * 4;
        if (r0 + 0 < n) Y[(long long)(r0 + 0) * 64 + lane] = acc0;
        if (r0 + 1 < n) Y[(long long)(r0 + 1) * 64 + lane] = acc1;
        if (r0 + 2 < n) Y[(long long)(r0 + 2) * 64 + lane] = acc2;
        if (r0 + 3 < n) Y[(long long)(r0 + 3) * 64 + lane] = acc3;
    }
}

// ---------------- aggregation: one wave per dst, lane = feature, 8-way MLP ----
__global__ __launch_bounds__(256) void agg_kernel(const float* __restrict__ T,
                                                  const int* __restrict__ offs,
                                                  const int2* __restrict__ meta,
                                                  const float* __restrict__ dinv,
                                                  const float* __restrict__ bias,
                                                  float* __restrict__ out, int n) {
    int v = blockIdx.x * 4 + (threadIdx.x >> 6);
    if (v >= n) return;
    int lane = threadIdx.x & 63;
    float di = dinv[v];
    float acc = di * di * T[(long long)v * D + lane];  // self-loop
    int j = offs[v], j1 = offs[v + 1];
    for (; j + 8 <= j1; j += 8) {
        int2 m0 = meta[j + 0], m1 = meta[j + 1], m2 = meta[j + 2], m3 = meta[j + 3];
        int2 m4 = meta[j + 4], m5 = meta[j + 5], m6 = meta[j + 6], m7 = meta[j + 7];
        float t0 = T[(long long)m0.x * D + lane];
        float t1 = T[(long long)m1.x * D + lane];
        float t2 = T[(long long)m2.x * D + lane];
        float t3 = T[(long long)m3.x * D + lane];
        float t4 = T[(long long)m4.x * D + lane];
        float t5 = T[(long long)m5.x * D + lane];
        float t6 = T[(long long)m6.x * D + lane];
        float t7 = T[(long long)m7.x * D + lane];
        acc += __int_as_float(m0.y) * t0;
        acc += __int_as_float(m1.y) * t1;
        acc += __int_as_float(m2.y) * t2;
        acc += __int_as_float(m3.y) * t3;
        acc += __int_as_float(m4.y) * t4;
        acc += __int_as_float(m5.y) * t5;
        acc += __int_as_float(m6.y) * t6;
        acc += __int_as_float(m7.y) * t7;
    }
    for (; j + 4 <= j1; j += 4) {
        int2 m0 = meta[j + 0], m1 = meta[j + 1], m2 = meta[j + 2], m3 = meta[j + 3];
        float t0 = T[(long long)m0.x * D + lane];
        float t1 = T[(long long)m1.x * D + lane];
        float t2 = T[(long long)m2.x * D + lane];
        float t3 = T[(long long)m3.x * D + lane];
        acc += __int_as_float(m0.y) * t0;
        acc += __int_as_float(m1.y) * t1;
        acc += __int_as_float(m2.y) * t2;
        acc += __int_as_float(m3.y) * t3;
    }
    for (; j < j1; j++) {
        int2 m = meta[j];
        acc += __int_as_float(m.y) * T[(long long)m.x * D + lane];
    }
    out[(long long)v * D + lane] = acc + bias[lane];
}

// ---------------- batchnorm stats ----------------
__global__ __launch_bounds__(256) void bnstats_kernel(const float* __restrict__ H,
                                                      float* __restrict__ stats, int n) {
    int f = threadIdx.x & 63;
    int r = threadIdx.x >> 6;
    float s = 0.f, q = 0.f;
    for (int node = blockIdx.x * 4 + r; node < n; node += gridDim.x * 4) {
        float x = H[(long long)node * D + f];
        s += x;
        q += x * x;
    }
    __shared__ float ls[256], lq[256];
    ls[threadIdx.x] = s;
    lq[threadIdx.x] = q;
    __syncthreads();
    if (r == 0) {
        s = ls[f] + ls[64 + f] + ls[128 + f] + ls[192 + f];
        q = lq[f] + lq[64 + f] + lq[128 + f] + lq[192 + f];
        atomicAdd(&stats[f], s);
        atomicAdd(&stats[64 + f], q);
    }
}

// ---------------- host ----------------
extern "C" void kernel_launch(void* const* d_in, const int* in_sizes, int n_in,
                              void* d_out, int out_size, void* d_ws, size_t ws_size,
                              hipStream_t stream) {
    const float* x = (const float*)d_in[0];
    const void* edges = d_in[1];
    const float* W1 = (const float*)d_in[3];
    const float* b1 = (const float*)d_in[4];
    const float* gamma1 = (const float*)d_in[5];
    const float* beta1 = (const float*)d_in[6];
    const float* W2 = (const float*)d_in[7];
    const float* b2 = (const float*)d_in[8];
    const float* gamma2 = (const float*)d_in[9];
    const float* beta2 = (const float*)d_in[10];
    const float* W3 = (const float*)d_in[11];
    const float* b3 = (const float*)d_in[12];

    const int N = in_sizes[0] / D;
    const int E = in_sizes[1] / 2;
    const float inv_n = 1.f / (float)N;

    char* ws = (char*)d_ws;
    size_t off = 0;
    auto alloc = [&](size_t bytes) -> void* {
        void* p = ws + off;
        off = (off + bytes + 255) & ~(size_t)255;
        return p;
    };
    float* dinv  = (float*)alloc((size_t)N * 4);
    int*   degi  = (int*)  alloc((size_t)N * 4);
    int*   offs  = (int*)  alloc((size_t)(N + 1) * 4);
    int*   fillp = (int*)  alloc((size_t)N * 4);
    int2*  meta  = (int2*) alloc((size_t)E * 8);
    int*   bsums = (int*)  alloc(1024 * 4);
    int*   flag  = (int*)  alloc(4);
    float* stats = (float*)alloc(128 * 4);
    float* bufA  = (float*)alloc((size_t)N * D * 4);
    float* hbuf  = (float*)d_out;  // ping-pong; fully overwritten each layer

    const int eb = (E + 255) / 256;
    const int nb256 = (N + 255) / 256;
    const int nb1024 = (N + 1023) / 1024;
    const int aggb = (N + 3) / 4;

    // ---- build CSR (once, reused 3x) ----
    hipMemsetAsync(degi, 0, (size_t)N * 4, stream);
    detect_kernel<<<1, 256, 0, stream>>>((const unsigned int*)edges, flag);
    deg_count_kernel<<<eb, 256, 0, stream>>>(edges, flag, degi, E);
    dinv_kernel<<<nb256, 256, 0, stream>>>(degi, dinv, N);
    scanA_kernel<<<nb1024, 1024, 0, stream>>>(degi, offs, bsums, N);
    scanB_kernel<<<1, 1024, 0, stream>>>(bsums, nb1024);
    scanC_kernel<<<nb1024, 1024, 0, stream>>>(offs, bsums, fillp, N, E);
    fill_kernel<<<eb, 256, 0, stream>>>(edges, flag, dinv, fillp, meta, E);

    // ---- layer 1 ----
    mm_bn_kernel<<<1024, 256, 0, stream>>>(x, W1, nullptr, nullptr, nullptr, 0, inv_n, bufA, N);
    agg_kernel<<<aggb, 256, 0, stream>>>(bufA, offs, meta, dinv, b1, hbuf, N);
    hipMemsetAsync(stats, 0, 128 * 4, stream);
    bnstats_kernel<<<512, 256, 0, stream>>>(hbuf, stats, N);

    // ---- layer 2 (BN1+ReLU fused into matmul staging) ----
    mm_bn_kernel<<<1024, 256, 0, stream>>>(hbuf, W2, stats, gamma1, beta1, 1, inv_n, bufA, N);
    agg_kernel<<<aggb, 256, 0, stream>>>(bufA, offs, meta, dinv, b2, hbuf, N);
    hipMemsetAsync(stats, 0, 128 * 4, stream);
    bnstats_kernel<<<512, 256, 0, stream>>>(hbuf, stats, N);

    // ---- layer 3 (BN2+ReLU fused; no BN after) ----
    mm_bn_kernel<<<1024, 256, 0, stream>>>(hbuf, W3, stats, gamma2, beta2, 1, inv_n, bufA, N);
    agg_kernel<<<aggb, 256, 0, stream>>>(bufA, offs, meta, dinv, b3, (float*)d_out, N);
}

// Round 4
// 486.529 us; speedup vs baseline: 2.9173x; 1.3812x over previous
//
#include <hip/hip_runtime.h>
#include <hip/hip_bf16.h>

#define D 64

typedef __attribute__((ext_vector_type(8))) short bf16x8;
typedef __attribute__((ext_vector_type(4))) float f32x4;

__device__ __forceinline__ short f2bf(float x) {
    unsigned u = __float_as_uint(x);
    unsigned r = (u + 0x7fffu + ((u >> 16) & 1u)) >> 16;  // RNE
    return (short)r;
}

// ---------------- int64-vs-int32 edge_index detection ----------------
__global__ void detect_kernel(const unsigned int* e32, int* flag) {
    __shared__ int nz;
    if (threadIdx.x == 0) nz = 0;
    __syncthreads();
    if (e32[2 * threadIdx.x + 1] != 0) nz = 1;
    __syncthreads();
    if (threadIdx.x == 0) *flag = (nz == 0) ? 1 : 0;
}

__device__ __forceinline__ int load_idx(const void* e, int is64, long long i) {
    if (is64) return (int)((const long long*)e)[i];
    return ((const int*)e)[i];
}

// ---------------- degree histogram ----------------
__global__ void deg_count_kernel(const void* edges, const int* flag, int* degi, int E) {
    int e = blockIdx.x * 256 + threadIdx.x;
    if (e >= E) return;
    int is64 = *flag;
    int dst = load_idx(edges, is64, (long long)E + e);
    atomicAdd(&degi[dst], 1);
}

__global__ void dinv_kernel(const int* degi, float* dinv, int n) {
    int v = blockIdx.x * 256 + threadIdx.x;
    if (v >= n) return;
    dinv[v] = rsqrtf((float)(degi[v] + 1));
}

// ---------------- exclusive scan ----------------
__global__ __launch_bounds__(1024) void scanA_kernel(const int* deg, int* offs, int* bsums, int n) {
    __shared__ int s[1024];
    int tid = threadIdx.x;
    int i = blockIdx.x * 1024 + tid;
    int v = (i < n) ? deg[i] : 0;
    s[tid] = v;
    __syncthreads();
    for (int d = 1; d < 1024; d <<= 1) {
        int t = (tid >= d) ? s[tid - d] : 0;
        __syncthreads();
        s[tid] += t;
        __syncthreads();
    }
    if (i < n) offs[i] = s[tid] - v;
    if (tid == 1023) bsums[blockIdx.x] = s[1023];
}

__global__ __launch_bounds__(1024) void scanB_kernel(int* bsums, int nb) {
    __shared__ int s[1024];
    int tid = threadIdx.x;
    int v = (tid < nb) ? bsums[tid] : 0;
    s[tid] = v;
    __syncthreads();
    for (int d = 1; d < 1024; d <<= 1) {
        int t = (tid >= d) ? s[tid - d] : 0;
        __syncthreads();
        s[tid] += t;
        __syncthreads();
    }
    if (tid < nb) bsums[tid] = s[tid] - v;
}

__global__ __launch_bounds__(1024) void scanC_kernel(int* offs, const int* bsums, int* fillptr,
                                                     int n, int E) {
    int i = blockIdx.x * 1024 + threadIdx.x;
    if (i < n) {
        int o = offs[i] + bsums[blockIdx.x];
        offs[i] = o;
        fillptr[i] = o;
    }
    if (i == 0) offs[n] = E;
}

// ---------------- CSR fill: packed (src, norm) meta ----------------
__global__ void fill_kernel(const void* edges, const int* flag, const float* dinv,
                            int* fillptr, int2* meta, int E) {
    int e = blockIdx.x * 256 + threadIdx.x;
    if (e >= E) return;
    int is64 = *flag;
    int s = load_idx(edges, is64, e);
    int d = load_idx(edges, is64, (long long)E + e);
    int pos = atomicAdd(&fillptr[d], 1);
    meta[pos] = make_int2(s, __float_as_int(dinv[s] * dinv[d]));
}

// ---------------- fused (BN+ReLU) -> [n,64]@[64,64] MFMA matmul ----------------
// One wave per 16-row tile: A loaded straight from global (wave-private, no LDS),
// BN+ReLU in fp32 during load, RNE cvt to bf16, 8x mfma_f32_16x16x32_bf16
// (2 K-steps x 4 N-tiles). B-fragments = whole W in 32 VGPRs. No spill risk
// (round-2/3 lesson: 64-deep fp32 wcol spilled at any reasonable occupancy).
// Layouts (HW-verified): A[m=lane&15][k=quad*8+j]; B[k=quad*8+j][n=lane&15];
// C col=lane&15, row=quad*4+reg.
__global__ __launch_bounds__(256) void mm_bn_kernel(
    const float* __restrict__ X, const float* __restrict__ W,
    const float* __restrict__ stats, const float* __restrict__ gamma,
    const float* __restrict__ beta, int use_bn, float inv_n,
    float* __restrict__ Y, int n) {
    int lane = threadIdx.x & 63;
    int m = lane & 15;
    int quad = lane >> 4;

    // per-lane BN affine params for the 16 features f = s*32 + quad*8 + j
    float sc[16], sh[16];
#pragma unroll
    for (int s = 0; s < 2; s++) {
#pragma unroll
        for (int j = 0; j < 8; j++) {
            float scale = 1.f, shift = 0.f;
            if (use_bn) {
                int f = s * 32 + quad * 8 + j;
                float mean = stats[f] * inv_n;
                float var = stats[64 + f] * inv_n - mean * mean;
                float rs = rsqrtf(var + 1e-5f);
                scale = rs * gamma[f];
                shift = beta[f] - mean * scale;
            }
            sc[s * 8 + j] = scale;
            sh[s * 8 + j] = shift;
        }
    }

    // B-fragments: all of W as bf16, 4 n-tiles x 2 k-steps (32 VGPRs)
    bf16x8 bfrag[4][2];
#pragma unroll
    for (int nt = 0; nt < 4; nt++) {
#pragma unroll
        for (int s = 0; s < 2; s++) {
#pragma unroll
            for (int j = 0; j < 8; j++) {
                int k = s * 32 + quad * 8 + j;
                bfrag[nt][s][j] = f2bf(W[k * 64 + nt * 16 + m]);
            }
        }
    }

    int wave = blockIdx.x * 4 + (threadIdx.x >> 6);
    int nwaves = gridDim.x * 4;
    int ntiles = (n + 15) >> 4;
    const f32x4 zero = {0.f, 0.f, 0.f, 0.f};

    for (int t = wave; t < ntiles; t += nwaves) {
        int r = t * 16 + m;
        if (r >= n) r = n - 1;  // redundant load; stores are guarded
        const float* xr = X + (long long)r * 64;
        f32x4 a0 = *(const f32x4*)(xr + quad * 8);
        f32x4 a1 = *(const f32x4*)(xr + quad * 8 + 4);
        f32x4 a2 = *(const f32x4*)(xr + 32 + quad * 8);
        f32x4 a3 = *(const f32x4*)(xr + 32 + quad * 8 + 4);

        float av[16];
#pragma unroll
        for (int j = 0; j < 4; j++) {
            av[j] = a0[j];
            av[4 + j] = a1[j];
            av[8 + j] = a2[j];
            av[12 + j] = a3[j];
        }
        bf16x8 A0, A1;
#pragma unroll
        for (int j = 0; j < 8; j++) {
            float v0 = av[j] * sc[j] + sh[j];
            float v1 = av[8 + j] * sc[8 + j] + sh[8 + j];
            if (use_bn) {
                v0 = fmaxf(v0, 0.f);
                v1 = fmaxf(v1, 0.f);
            }
            A0[j] = f2bf(v0);
            A1[j] = f2bf(v1);
        }

        f32x4 acc[4];
#pragma unroll
        for (int nt = 0; nt < 4; nt++) {
            acc[nt] = __builtin_amdgcn_mfma_f32_16x16x32_bf16(A0, bfrag[nt][0], zero, 0, 0, 0);
            acc[nt] = __builtin_amdgcn_mfma_f32_16x16x32_bf16(A1, bfrag[nt][1], acc[nt], 0, 0, 0);
        }

        int row0 = t * 16 + quad * 4;
#pragma unroll
        for (int nt = 0; nt < 4; nt++) {
#pragma unroll
            for (int i = 0; i < 4; i++) {
                int rr = row0 + i;
                if (rr < n) Y[(long long)rr * 64 + nt * 16 + m] = acc[nt][i];
            }
        }
    }
}

// ---------------- aggregation: one wave per dst, lane = feature, 8-way MLP ----
__global__ __launch_bounds__(256) void agg_kernel(const float* __restrict__ T,
                                                  const int* __restrict__ offs,
                                                  const int2* __restrict__ meta,
                                                  const float* __restrict__ dinv,
                                                  const float* __restrict__ bias,
                                                  float* __restrict__ out, int n) {
    int v = blockIdx.x * 4 + (threadIdx.x >> 6);
    if (v >= n) return;
    int lane = threadIdx.x & 63;
    float di = dinv[v];
    float acc = di * di * T[(long long)v * D + lane];  // self-loop
    int j = offs[v], j1 = offs[v + 1];
    for (; j + 8 <= j1; j += 8) {
        int2 m0 = meta[j + 0], m1 = meta[j + 1], m2 = meta[j + 2], m3 = meta[j + 3];
        int2 m4 = meta[j + 4], m5 = meta[j + 5], m6 = meta[j + 6], m7 = meta[j + 7];
        float t0 = T[(long long)m0.x * D + lane];
        float t1 = T[(long long)m1.x * D + lane];
        float t2 = T[(long long)m2.x * D + lane];
        float t3 = T[(long long)m3.x * D + lane];
        float t4 = T[(long long)m4.x * D + lane];
        float t5 = T[(long long)m5.x * D + lane];
        float t6 = T[(long long)m6.x * D + lane];
        float t7 = T[(long long)m7.x * D + lane];
        acc += __int_as_float(m0.y) * t0;
        acc += __int_as_float(m1.y) * t1;
        acc += __int_as_float(m2.y) * t2;
        acc += __int_as_float(m3.y) * t3;
        acc += __int_as_float(m4.y) * t4;
        acc += __int_as_float(m5.y) * t5;
        acc += __int_as_float(m6.y) * t6;
        acc += __int_as_float(m7.y) * t7;
    }
    for (; j + 4 <= j1; j += 4) {
        int2 m0 = meta[j + 0], m1 = meta[j + 1], m2 = meta[j + 2], m3 = meta[j + 3];
        float t0 = T[(long long)m0.x * D + lane];
        float t1 = T[(long long)m1.x * D + lane];
        float t2 = T[(long long)m2.x * D + lane];
        float t3 = T[(long long)m3.x * D + lane];
        acc += __int_as_float(m0.y) * t0;
        acc += __int_as_float(m1.y) * t1;
        acc += __int_as_float(m2.y) * t2;
        acc += __int_as_float(m3.y) * t3;
    }
    for (; j < j1; j++) {
        int2 m = meta[j];
        acc += __int_as_float(m.y) * T[(long long)m.x * D + lane];
    }
    out[(long long)v * D + lane] = acc + bias[lane];
}

// ---------------- batchnorm stats ----------------
__global__ __launch_bounds__(256) void bnstats_kernel(const float* __restrict__ H,
                                                      float* __restrict__ stats, int n) {
    int f = threadIdx.x & 63;
    int r = threadIdx.x >> 6;
    float s = 0.f, q = 0.f;
    for (int node = blockIdx.x * 4 + r; node < n; node += gridDim.x * 4) {
        float x = H[(long long)node * D + f];
        s += x;
        q += x * x;
    }
    __shared__ float ls[256], lq[256];
    ls[threadIdx.x] = s;
    lq[threadIdx.x] = q;
    __syncthreads();
    if (r == 0) {
        s = ls[f] + ls[64 + f] + ls[128 + f] + ls[192 + f];
        q = lq[f] + lq[64 + f] + lq[128 + f] + lq[192 + f];
        atomicAdd(&stats[f], s);
        atomicAdd(&stats[64 + f], q);
    }
}

// ---------------- host ----------------
extern "C" void kernel_launch(void* const* d_in, const int* in_sizes, int n_in,
                              void* d_out, int out_size, void* d_ws, size_t ws_size,
                              hipStream_t stream) {
    const float* x = (const float*)d_in[0];
    const void* edges = d_in[1];
    const float* W1 = (const float*)d_in[3];
    const float* b1 = (const float*)d_in[4];
    const float* gamma1 = (const float*)d_in[5];
    const float* beta1 = (const float*)d_in[6];
    const float* W2 = (const float*)d_in[7];
    const float* b2 = (const float*)d_in[8];
    const float* gamma2 = (const float*)d_in[9];
    const float* beta2 = (const float*)d_in[10];
    const float* W3 = (const float*)d_in[11];
    const float* b3 = (const float*)d_in[12];

    const int N = in_sizes[0] / D;
    const int E = in_sizes[1] / 2;
    const float inv_n = 1.f / (float)N;

    char* ws = (char*)d_ws;
    size_t off = 0;
    auto alloc = [&](size_t bytes) -> void* {
        void* p = ws + off;
        off = (off + bytes + 255) & ~(size_t)255;
        return p;
    };
    float* dinv  = (float*)alloc((size_t)N * 4);
    int*   degi  = (int*)  alloc((size_t)N * 4);
    int*   offs  = (int*)  alloc((size_t)(N + 1) * 4);
    int*   fillp = (int*)  alloc((size_t)N * 4);
    int2*  meta  = (int2*) alloc((size_t)E * 8);
    int*   bsums = (int*)  alloc(1024 * 4);
    int*   flag  = (int*)  alloc(4);
    float* stats = (float*)alloc(128 * 4);
    float* bufA  = (float*)alloc((size_t)N * D * 4);
    float* hbuf  = (float*)d_out;  // ping-pong; fully overwritten each layer

    const int eb = (E + 255) / 256;
    const int nb256 = (N + 255) / 256;
    const int nb1024 = (N + 1023) / 1024;
    const int aggb = (N + 3) / 4;

    // ---- build CSR (once, reused 3x) ----
    hipMemsetAsync(degi, 0, (size_t)N * 4, stream);
    detect_kernel<<<1, 256, 0, stream>>>((const unsigned int*)edges, flag);
    deg_count_kernel<<<eb, 256, 0, stream>>>(edges, flag, degi, E);
    dinv_kernel<<<nb256, 256, 0, stream>>>(degi, dinv, N);
    scanA_kernel<<<nb1024, 1024, 0, stream>>>(degi, offs, bsums, N);
    scanB_kernel<<<1, 1024, 0, stream>>>(bsums, nb1024);
    scanC_kernel<<<nb1024, 1024, 0, stream>>>(offs, bsums, fillp, N, E);
    fill_kernel<<<eb, 256, 0, stream>>>(edges, flag, dinv, fillp, meta, E);

    // ---- layer 1 ----
    mm_bn_kernel<<<512, 256, 0, stream>>>(x, W1, nullptr, nullptr, nullptr, 0, inv_n, bufA, N);
    agg_kernel<<<aggb, 256, 0, stream>>>(bufA, offs, meta, dinv, b1, hbuf, N);
    hipMemsetAsync(stats, 0, 128 * 4, stream);
    bnstats_kernel<<<512, 256, 0, stream>>>(hbuf, stats, N);

    // ---- layer 2 (BN1+ReLU fused into matmul A-load) ----
    mm_bn_kernel<<<512, 256, 0, stream>>>(hbuf, W2, stats, gamma1, beta1, 1, inv_n, bufA, N);
    agg_kernel<<<aggb, 256, 0, stream>>>(bufA, offs, meta, dinv, b2, hbuf, N);
    hipMemsetAsync(stats, 0, 128 * 4, stream);
    bnstats_kernel<<<512, 256, 0, stream>>>(hbuf, stats, N);

    // ---- layer 3 (BN2+ReLU fused; no BN after) ----
    mm_bn_kernel<<<512, 256, 0, stream>>>(hbuf, W3, stats, gamma2, beta2, 1, inv_n, bufA, N);
    agg_kernel<<<aggb, 256, 0, stream>>>(bufA, offs, meta, dinv, b3, (float*)d_out, N);
}

// Round 5
// 469.201 us; speedup vs baseline: 3.0250x; 1.0369x over previous
//
#include <hip/hip_runtime.h>
#include <hip/hip_bf16.h>

#define D 64

typedef __attribute__((ext_vector_type(8))) short bf16x8;
typedef __attribute__((ext_vector_type(4))) float f32x4;

__device__ __forceinline__ short f2bf(float x) {
    unsigned u = __float_as_uint(x);
    unsigned r = (u + 0x7fffu + ((u >> 16) & 1u)) >> 16;  // RNE
    return (short)r;
}
__device__ __forceinline__ float bf2f(unsigned short u) {
    return __uint_as_float((unsigned)u << 16);
}

// ---------------- int64-vs-int32 edge_index detection ----------------
__global__ void detect_kernel(const unsigned int* e32, int* flag) {
    __shared__ int nz;
    if (threadIdx.x == 0) nz = 0;
    __syncthreads();
    if (e32[2 * threadIdx.x + 1] != 0) nz = 1;
    __syncthreads();
    if (threadIdx.x == 0) *flag = (nz == 0) ? 1 : 0;
}

__device__ __forceinline__ int load_idx(const void* e, int is64, long long i) {
    if (is64) return (int)((const long long*)e)[i];
    return ((const int*)e)[i];
}

// ---------------- degree histogram ----------------
__global__ void deg_count_kernel(const void* edges, const int* flag, int* degi, int E) {
    int e = blockIdx.x * 256 + threadIdx.x;
    if (e >= E) return;
    int is64 = *flag;
    int dst = load_idx(edges, is64, (long long)E + e);
    atomicAdd(&degi[dst], 1);
}

__global__ void dinv_kernel(const int* degi, float* dinv, int n) {
    int v = blockIdx.x * 256 + threadIdx.x;
    if (v >= n) return;
    dinv[v] = rsqrtf((float)(degi[v] + 1));
}

// ---------------- exclusive scan ----------------
__global__ __launch_bounds__(1024) void scanA_kernel(const int* deg, int* offs, int* bsums, int n) {
    __shared__ int s[1024];
    int tid = threadIdx.x;
    int i = blockIdx.x * 1024 + tid;
    int v = (i < n) ? deg[i] : 0;
    s[tid] = v;
    __syncthreads();
    for (int d = 1; d < 1024; d <<= 1) {
        int t = (tid >= d) ? s[tid - d] : 0;
        __syncthreads();
        s[tid] += t;
        __syncthreads();
    }
    if (i < n) offs[i] = s[tid] - v;
    if (tid == 1023) bsums[blockIdx.x] = s[1023];
}

__global__ __launch_bounds__(1024) void scanB_kernel(int* bsums, int nb) {
    __shared__ int s[1024];
    int tid = threadIdx.x;
    int v = (tid < nb) ? bsums[tid] : 0;
    s[tid] = v;
    __syncthreads();
    for (int d = 1; d < 1024; d <<= 1) {
        int t = (tid >= d) ? s[tid - d] : 0;
        __syncthreads();
        s[tid] += t;
        __syncthreads();
    }
    if (tid < nb) bsums[tid] = s[tid] - v;
}

__global__ __launch_bounds__(1024) void scanC_kernel(int* offs, const int* bsums, int* fillptr,
                                                     int n, int E) {
    int i = blockIdx.x * 1024 + threadIdx.x;
    if (i < n) {
        int o = offs[i] + bsums[blockIdx.x];
        offs[i] = o;
        fillptr[i] = o;
    }
    if (i == 0) offs[n] = E;
}

// ---------------- CSR fill: packed (src, norm) meta ----------------
__global__ void fill_kernel(const void* edges, const int* flag, const float* dinv,
                            int* fillptr, int2* meta, int E) {
    int e = blockIdx.x * 256 + threadIdx.x;
    if (e >= E) return;
    int is64 = *flag;
    int s = load_idx(edges, is64, e);
    int d = load_idx(edges, is64, (long long)E + e);
    int pos = atomicAdd(&fillptr[d], 1);
    meta[pos] = make_int2(s, __float_as_int(dinv[s] * dinv[d]));
}

// ---------------- fused (BN+ReLU) -> [n,64]@[64,64] MFMA matmul ----------------
// One wave per 16-row tile; A from global (fp32), BN+ReLU in fp32, cvt bf16,
// 8x mfma_f32_16x16x32_bf16. Output written as bf16 (message buffer) — halves
// the downstream gather traffic in agg_kernel.
// Layouts (HW-verified): A[m=lane&15][k=quad*8+j]; B[k=quad*8+j][n=lane&15];
// C col=lane&15, row=quad*4+reg.
__global__ __launch_bounds__(256) void mm_bn_kernel(
    const float* __restrict__ X, const float* __restrict__ W,
    const float* __restrict__ stats, const float* __restrict__ gamma,
    const float* __restrict__ beta, int use_bn, float inv_n,
    unsigned short* __restrict__ Y, int n) {
    int lane = threadIdx.x & 63;
    int m = lane & 15;
    int quad = lane >> 4;

    // per-lane BN affine params for the 16 features f = s*32 + quad*8 + j
    float sc[16], sh[16];
#pragma unroll
    for (int s = 0; s < 2; s++) {
#pragma unroll
        for (int j = 0; j < 8; j++) {
            float scale = 1.f, shift = 0.f;
            if (use_bn) {
                int f = s * 32 + quad * 8 + j;
                float mean = stats[f] * inv_n;
                float var = stats[64 + f] * inv_n - mean * mean;
                float rs = rsqrtf(var + 1e-5f);
                scale = rs * gamma[f];
                shift = beta[f] - mean * scale;
            }
            sc[s * 8 + j] = scale;
            sh[s * 8 + j] = shift;
        }
    }

    // B-fragments: all of W as bf16, 4 n-tiles x 2 k-steps (32 VGPRs)
    bf16x8 bfrag[4][2];
#pragma unroll
    for (int nt = 0; nt < 4; nt++) {
#pragma unroll
        for (int s = 0; s < 2; s++) {
#pragma unroll
            for (int j = 0; j < 8; j++) {
                int k = s * 32 + quad * 8 + j;
                bfrag[nt][s][j] = f2bf(W[k * 64 + nt * 16 + m]);
            }
        }
    }

    int wave = blockIdx.x * 4 + (threadIdx.x >> 6);
    int nwaves = gridDim.x * 4;
    int ntiles = (n + 15) >> 4;
    const f32x4 zero = {0.f, 0.f, 0.f, 0.f};

    for (int t = wave; t < ntiles; t += nwaves) {
        int r = t * 16 + m;
        if (r >= n) r = n - 1;  // redundant load; stores are guarded
        const float* xr = X + (long long)r * 64;
        f32x4 a0 = *(const f32x4*)(xr + quad * 8);
        f32x4 a1 = *(const f32x4*)(xr + quad * 8 + 4);
        f32x4 a2 = *(const f32x4*)(xr + 32 + quad * 8);
        f32x4 a3 = *(const f32x4*)(xr + 32 + quad * 8 + 4);

        float av[16];
#pragma unroll
        for (int j = 0; j < 4; j++) {
            av[j] = a0[j];
            av[4 + j] = a1[j];
            av[8 + j] = a2[j];
            av[12 + j] = a3[j];
        }
        bf16x8 A0, A1;
#pragma unroll
        for (int j = 0; j < 8; j++) {
            float v0 = av[j] * sc[j] + sh[j];
            float v1 = av[8 + j] * sc[8 + j] + sh[8 + j];
            if (use_bn) {
                v0 = fmaxf(v0, 0.f);
                v1 = fmaxf(v1, 0.f);
            }
            A0[j] = f2bf(v0);
            A1[j] = f2bf(v1);
        }

        f32x4 acc[4];
#pragma unroll
        for (int nt = 0; nt < 4; nt++) {
            acc[nt] = __builtin_amdgcn_mfma_f32_16x16x32_bf16(A0, bfrag[nt][0], zero, 0, 0, 0);
            acc[nt] = __builtin_amdgcn_mfma_f32_16x16x32_bf16(A1, bfrag[nt][1], acc[nt], 0, 0, 0);
        }

        int row0 = t * 16 + quad * 4;
#pragma unroll
        for (int nt = 0; nt < 4; nt++) {
#pragma unroll
            for (int i = 0; i < 4; i++) {
                int rr = row0 + i;
                if (rr < n)
                    Y[(long long)rr * 64 + nt * 16 + m] = (unsigned short)f2bf(acc[nt][i]);
            }
        }
    }
}

// ---------------- aggregation: one wave per dst, lane = feature, 8-way MLP ----
// T is bf16 (message buffer): 128 B/row gather instead of 256 B. Accumulate fp32.
__global__ __launch_bounds__(256) void agg_kernel(const unsigned short* __restrict__ T,
                                                  const int* __restrict__ offs,
                                                  const int2* __restrict__ meta,
                                                  const float* __restrict__ dinv,
                                                  const float* __restrict__ bias,
                                                  float* __restrict__ out, int n) {
    int v = blockIdx.x * 4 + (threadIdx.x >> 6);
    if (v >= n) return;
    int lane = threadIdx.x & 63;
    float di = dinv[v];
    float acc = di * di * bf2f(T[(long long)v * D + lane]);  // self-loop
    int j = offs[v], j1 = offs[v + 1];
    for (; j + 8 <= j1; j += 8) {
        int2 m0 = meta[j + 0], m1 = meta[j + 1], m2 = meta[j + 2], m3 = meta[j + 3];
        int2 m4 = meta[j + 4], m5 = meta[j + 5], m6 = meta[j + 6], m7 = meta[j + 7];
        float t0 = bf2f(T[(long long)m0.x * D + lane]);
        float t1 = bf2f(T[(long long)m1.x * D + lane]);
        float t2 = bf2f(T[(long long)m2.x * D + lane]);
        float t3 = bf2f(T[(long long)m3.x * D + lane]);
        float t4 = bf2f(T[(long long)m4.x * D + lane]);
        float t5 = bf2f(T[(long long)m5.x * D + lane]);
        float t6 = bf2f(T[(long long)m6.x * D + lane]);
        float t7 = bf2f(T[(long long)m7.x * D + lane]);
        acc += __int_as_float(m0.y) * t0;
        acc += __int_as_float(m1.y) * t1;
        acc += __int_as_float(m2.y) * t2;
        acc += __int_as_float(m3.y) * t3;
        acc += __int_as_float(m4.y) * t4;
        acc += __int_as_float(m5.y) * t5;
        acc += __int_as_float(m6.y) * t6;
        acc += __int_as_float(m7.y) * t7;
    }
    for (; j + 4 <= j1; j += 4) {
        int2 m0 = meta[j + 0], m1 = meta[j + 1], m2 = meta[j + 2], m3 = meta[j + 3];
        float t0 = bf2f(T[(long long)m0.x * D + lane]);
        float t1 = bf2f(T[(long long)m1.x * D + lane]);
        float t2 = bf2f(T[(long long)m2.x * D + lane]);
        float t3 = bf2f(T[(long long)m3.x * D + lane]);
        acc += __int_as_float(m0.y) * t0;
        acc += __int_as_float(m1.y) * t1;
        acc += __int_as_float(m2.y) * t2;
        acc += __int_as_float(m3.y) * t3;
    }
    for (; j < j1; j++) {
        int2 m = meta[j];
        acc += __int_as_float(m.y) * bf2f(T[(long long)m.x * D + lane]);
    }
    out[(long long)v * D + lane] = acc + bias[lane];
}

// ---------------- batchnorm stats ----------------
__global__ __launch_bounds__(256) void bnstats_kernel(const float* __restrict__ H,
                                                      float* __restrict__ stats, int n) {
    int f = threadIdx.x & 63;
    int r = threadIdx.x >> 6;
    float s = 0.f, q = 0.f;
    for (int node = blockIdx.x * 4 + r; node < n; node += gridDim.x * 4) {
        float x = H[(long long)node * D + f];
        s += x;
        q += x * x;
    }
    __shared__ float ls[256], lq[256];
    ls[threadIdx.x] = s;
    lq[threadIdx.x] = q;
    __syncthreads();
    if (r == 0) {
        s = ls[f] + ls[64 + f] + ls[128 + f] + ls[192 + f];
        q = lq[f] + lq[64 + f] + lq[128 + f] + lq[192 + f];
        atomicAdd(&stats[f], s);
        atomicAdd(&stats[64 + f], q);
    }
}

// ---------------- host ----------------
extern "C" void kernel_launch(void* const* d_in, const int* in_sizes, int n_in,
                              void* d_out, int out_size, void* d_ws, size_t ws_size,
                              hipStream_t stream) {
    const float* x = (const float*)d_in[0];
    const void* edges = d_in[1];
    const float* W1 = (const float*)d_in[3];
    const float* b1 = (const float*)d_in[4];
    const float* gamma1 = (const float*)d_in[5];
    const float* beta1 = (const float*)d_in[6];
    const float* W2 = (const float*)d_in[7];
    const float* b2 = (const float*)d_in[8];
    const float* gamma2 = (const float*)d_in[9];
    const float* beta2 = (const float*)d_in[10];
    const float* W3 = (const float*)d_in[11];
    const float* b3 = (const float*)d_in[12];

    const int N = in_sizes[0] / D;
    const int E = in_sizes[1] / 2;
    const float inv_n = 1.f / (float)N;

    char* ws = (char*)d_ws;
    size_t off = 0;
    auto alloc = [&](size_t bytes) -> void* {
        void* p = ws + off;
        off = (off + bytes + 255) & ~(size_t)255;
        return p;
    };
    float* dinv  = (float*)alloc((size_t)N * 4);
    int*   degi  = (int*)  alloc((size_t)N * 4);
    int*   offs  = (int*)  alloc((size_t)(N + 1) * 4);
    int*   fillp = (int*)  alloc((size_t)N * 4);
    int2*  meta  = (int2*) alloc((size_t)E * 8);
    int*   bsums = (int*)  alloc(1024 * 4);
    int*   flag  = (int*)  alloc(4);
    float* stats = (float*)alloc(128 * 4);
    unsigned short* bufA = (unsigned short*)alloc((size_t)N * D * 2);  // bf16 messages
    float* hbuf  = (float*)d_out;  // fp32 ping-pong; fully overwritten each layer

    const int eb = (E + 255) / 256;
    const int nb256 = (N + 255) / 256;
    const int nb1024 = (N + 1023) / 1024;
    const int aggb = (N + 3) / 4;

    // ---- build CSR (once, reused 3x) ----
    hipMemsetAsync(degi, 0, (size_t)N * 4, stream);
    detect_kernel<<<1, 256, 0, stream>>>((const unsigned int*)edges, flag);
    deg_count_kernel<<<eb, 256, 0, stream>>>(edges, flag, degi, E);
    dinv_kernel<<<nb256, 256, 0, stream>>>(degi, dinv, N);
    scanA_kernel<<<nb1024, 1024, 0, stream>>>(degi, offs, bsums, N);
    scanB_kernel<<<1, 1024, 0, stream>>>(bsums, nb1024);
    scanC_kernel<<<nb1024, 1024, 0, stream>>>(offs, bsums, fillp, N, E);
    fill_kernel<<<eb, 256, 0, stream>>>(edges, flag, dinv, fillp, meta, E);

    // ---- layer 1 ----
    mm_bn_kernel<<<512, 256, 0, stream>>>(x, W1, nullptr, nullptr, nullptr, 0, inv_n, bufA, N);
    agg_kernel<<<aggb, 256, 0, stream>>>(bufA, offs, meta, dinv, b1, hbuf, N);
    hipMemsetAsync(stats, 0, 128 * 4, stream);
    bnstats_kernel<<<512, 256, 0, stream>>>(hbuf, stats, N);

    // ---- layer 2 (BN1+ReLU fused into matmul A-load) ----
    mm_bn_kernel<<<512, 256, 0, stream>>>(hbuf, W2, stats, gamma1, beta1, 1, inv_n, bufA, N);
    agg_kernel<<<aggb, 256, 0, stream>>>(bufA, offs, meta, dinv, b2, hbuf, N);
    hipMemsetAsync(stats, 0, 128 * 4, stream);
    bnstats_kernel<<<512, 256, 0, stream>>>(hbuf, stats, N);

    // ---- layer 3 (BN2+ReLU fused; no BN after) ----
    mm_bn_kernel<<<512, 256, 0, stream>>>(hbuf, W3, stats, gamma2, beta2, 1, inv_n, bufA, N);
    agg_kernel<<<aggb, 256, 0, stream>>>(bufA, offs, meta, dinv, b3, (float*)d_out, N);
}